// Round 11
// baseline (267.245 us; speedup 1.0000x reference)
//
#include <hip/hip_runtime.h>
#include <hip/hip_bf16.h>
#include <math.h>

typedef unsigned short ushort_t;
typedef short short8 __attribute__((ext_vector_type(8)));
typedef float f32x4 __attribute__((ext_vector_type(4)));

__device__ __forceinline__ float b2f(ushort_t u) {
  union { unsigned u; float f; } v; v.u = ((unsigned)u) << 16; return v.f;
}
__device__ __forceinline__ ushort_t f2b(float f) {
  union { float f; unsigned u; } v; v.f = f;
  unsigned r = (v.u + 0x7FFFu + ((v.u >> 16) & 1u)) >> 16;
  return (ushort_t)r;
}
// fast GELU: tanh form, one exp2 — max abs err ~3e-4
__device__ __forceinline__ float gelu_fast(float v) {
  float u = 0.7978845608f * (v + 0.044715f * v * v * v);
  float a = fabsf(u);
  float t = exp2f(a * -2.8853900817779268f);
  float th = (1.f - t) / (1.f + t);
  th = copysignf(th, u);
  return 0.5f * v * (1.f + th);
}

union U16x8 { uint4 v; ushort_t s[8]; };

typedef const __attribute__((address_space(1))) unsigned int glb_u32;
typedef __attribute__((address_space(3))) unsigned int lds_u32;
__device__ __forceinline__ void gl_lds16(const ushort_t* g, ushort_t* l) {
  __builtin_amdgcn_global_load_lds((glb_u32*)g, (lds_u32*)l, 16, 0, 0);
}

// ------------- fused prep: cvt4 (3072 blk) + LayerNorm1 (2048 blk) + kw (8192 blk) -------------
__global__ __launch_bounds__(256) void prep_kernel(const float* __restrict__ s0,
                                                   const float* __restrict__ s1,
                                                   const float* __restrict__ s2,
                                                   const float* __restrict__ s3,
                                                   ushort_t* __restrict__ d0,
                                                   ushort_t* __restrict__ d1,
                                                   ushort_t* __restrict__ d2,
                                                   ushort_t* __restrict__ d3,
                                                   const float* __restrict__ x,
                                                   const float* __restrict__ w,
                                                   const float* __restrict__ b,
                                                   ushort_t* __restrict__ xnout,
                                                   const int* __restrict__ posv,
                                                   const int* __restrict__ posh,
                                                   ushort_t* __restrict__ kw) {
  int bid = blockIdx.x;
  int tid = threadIdx.x;
  if (bid < 3072) {
    long i = (long)bid * 256 + tid;
    const float* s; ushort_t* d; long off;
    if (i < 196608)       { s = s0; d = d0; off = i; }
    else if (i < 262144)  { s = s1; d = d1; off = i - 196608; }
    else if (i < 524288)  { s = s2; d = d2; off = i - 262144; }
    else                  { s = s3; d = d3; off = i - 524288; }
    float4 f = *(const float4*)(s + off * 4);
    union { uint2 v; ushort_t s[4]; } o;
    o.s[0] = f2b(f.x); o.s[1] = f2b(f.y); o.s[2] = f2b(f.z); o.s[3] = f2b(f.w);
    *(uint2*)(d + off * 4) = o.v;
  } else if (bid < 5120) {
    int wave = tid >> 6, lane = tid & 63;
    long token = (long)(bid - 3072) * 4 + wave;
    const float* xr = x + token * 512 + lane * 8;
    float4 a0 = *(const float4*)xr;
    float4 a1 = *(const float4*)(xr + 4);
    float xf[8] = {a0.x, a0.y, a0.z, a0.w, a1.x, a1.y, a1.z, a1.w};
    float s = 0.f, sq = 0.f;
#pragma unroll
    for (int i = 0; i < 8; i++) { s += xf[i]; sq += xf[i] * xf[i]; }
#pragma unroll
    for (int off = 1; off < 64; off <<= 1) { s += __shfl_xor(s, off); sq += __shfl_xor(sq, off); }
    float m = s * (1.f / 512.f);
    float var = sq * (1.f / 512.f) - m * m;
    float rs = rsqrtf(var + 1e-5f);
    float4 w0 = *(const float4*)(w + lane * 8);
    float4 w1v = *(const float4*)(w + lane * 8 + 4);
    float4 b0 = *(const float4*)(b + lane * 8);
    float4 b1v = *(const float4*)(b + lane * 8 + 4);
    float wf[8] = {w0.x, w0.y, w0.z, w0.w, w1v.x, w1v.y, w1v.z, w1v.w};
    float bf[8] = {b0.x, b0.y, b0.z, b0.w, b1v.x, b1v.y, b1v.z, b1v.w};
    U16x8 o;
#pragma unroll
    for (int i = 0; i < 8; i++) o.s[i] = f2b((xf[i] - m) * rs * wf[i] + bf[i]);
    *(uint4*)(xnout + token * 512 + lane * 8) = o.v;
  } else {
    int bb = bid - 5120;
    int bz = bb >> 10, i = bb & 1023;
    const int* pv = posv + bz * 1024;
    const int* ph = posh + bz * 1024;
    int pvi = pv[i], phi = ph[i];
    int j0 = tid * 4;
    int4 vj = *(const int4*)(pv + j0);
    int4 hj = *(const int4*)(ph + j0);
    int vv[4] = {vj.x, vj.y, vj.z, vj.w};
    int hh[4] = {hj.x, hj.y, hj.z, hj.w};
    float e[4]; float loc = 0.f;
#pragma unroll
    for (int u = 0; u < 4; u++) {
      int dv = pvi - vv[u], dh = phi - hh[u];
      e[u] = expf((float)(dv * dv + dh * dh) * (-1.f / 512.f));
      loc += e[u];
    }
#pragma unroll
    for (int off = 1; off < 64; off <<= 1) loc += __shfl_xor(loc, off);
    __shared__ float wsum[4];
    __shared__ float tot;
    if ((tid & 63) == 0) wsum[tid >> 6] = loc;
    __syncthreads();
    if (tid == 0) tot = wsum[0] + wsum[1] + wsum[2] + wsum[3];
    __syncthreads();
    float inv = 1.f / tot;
    union { uint2 v; ushort_t s[4]; } o;
#pragma unroll
    for (int u = 0; u < 4; u++) o.s[u] = f2b(e[u] * inv);
    *(uint2*)&kw[((long)(bz * 1024 + i)) * 1024 + j0] = o.v;
  }
}

// ---------------- LayerNorm (bf16 in, bf16 out) ----------------
__global__ __launch_bounds__(256) void ln_b_kernel(const ushort_t* __restrict__ x,
                                                   const float* __restrict__ w,
                                                   const float* __restrict__ b,
                                                   ushort_t* __restrict__ out) {
  int tid = threadIdx.x, wave = tid >> 6, lane = tid & 63;
  long token = (long)blockIdx.x * 4 + wave;
  U16x8 ux; ux.v = *(const uint4*)(x + token * 512 + lane * 8);
  float xf[8], s = 0.f, sq = 0.f;
#pragma unroll
  for (int i = 0; i < 8; i++) { xf[i] = b2f(ux.s[i]); s += xf[i]; sq += xf[i] * xf[i]; }
#pragma unroll
  for (int off = 1; off < 64; off <<= 1) { s += __shfl_xor(s, off); sq += __shfl_xor(sq, off); }
  float m = s * (1.f / 512.f);
  float var = sq * (1.f / 512.f) - m * m;
  float rs = rsqrtf(var + 1e-5f);
  float4 w0 = *(const float4*)(w + lane * 8);
  float4 w1v = *(const float4*)(w + lane * 8 + 4);
  float4 b0 = *(const float4*)(b + lane * 8);
  float4 b1v = *(const float4*)(b + lane * 8 + 4);
  float wf[8] = {w0.x, w0.y, w0.z, w0.w, w1v.x, w1v.y, w1v.z, w1v.w};
  float bf[8] = {b0.x, b0.y, b0.z, b0.w, b1v.x, b1v.y, b1v.z, b1v.w};
  U16x8 o;
#pragma unroll
  for (int i = 0; i < 8; i++) o.s[i] = f2b((xf[i] - m) * rs * wf[i] + bf[i]);
  *(uint4*)(out + token * 512 + lane * 8) = o.v;
}

// ---- merged qkv GEMM (blocks 0..1535, v written TRANSPOSED -> vT direct) + trXn (1536..2559) ----
// qkv: M=8192 N=1536 K=512, 64x128 quad single-barrier (r7-verified body).
// v-epilogue writes [bh][d][t] layout directly: per block, fixed d covers 64 consecutive t
// = full 128B lines -> L2 write-combines the scattered 2B stores. Kills trV + vtmp roundtrip.
// trXn: xn[z][1024][512] -> xnT[z][512][1024], independent of qkv (input = prep's xn).
__global__ __launch_bounds__(256) void qt_kernel(const ushort_t* __restrict__ xn,
                                                 const ushort_t* __restrict__ inwb,
                                                 const float* __restrict__ in_b,
                                                 ushort_t* __restrict__ qp,
                                                 ushort_t* __restrict__ kp,
                                                 ushort_t* __restrict__ vTp,
                                                 ushort_t* __restrict__ xnT) {
  __shared__ __align__(16) ushort_t smem[24576];   // 48 KB union
  int bid = blockIdx.x;
  int tid = threadIdx.x, wv = tid >> 6, lane = tid & 63;
  int quad = lane >> 4, l15 = lane & 15;

  if (bid < 1536) {
    // ----- qkv GEMM -----
    ushort_t* As = smem;            // 4 bufs x 2048
    ushort_t* Bs = smem + 8192;     // 4 bufs x 4096
    int m0 = (bid & 127) * 64;
    int n0 = (bid >> 7) * 128;
    int wm = (wv & 1) * 32, wn = (wv >> 1) * 64;
    f32x4 acc[2][4];
#pragma unroll
    for (int i = 0; i < 2; i++)
#pragma unroll
      for (int j = 0; j < 4; j++)
#pragma unroll
        for (int r = 0; r < 4; r++) acc[i][j][r] = 0.f;

    int srow = tid >> 2;
    int sc = ((tid & 3) ^ ((tid >> 3) & 3)) * 8;
    const ushort_t* ga = xn + (long)(m0 + srow) * 512 + sc;
    const ushort_t* gb = inwb + (long)(n0 + srow) * 512 + sc;
    const long a64 = 64L * 512, b64 = 64L * 512;
    int aswz = (quad ^ ((l15 >> 1) & 3)) * 8;

#pragma unroll
    for (int s = 0; s < 2; s++) {
      gl_lds16(ga + s * 32, As + s * 2048 + wv * 512);
#pragma unroll
      for (int rr = 0; rr < 2; rr++)
        gl_lds16(gb + s * 32 + rr * b64, Bs + s * 4096 + rr * 2048 + wv * 512);
    }

    for (int ks = 0; ks < 16; ks += 2) {
      asm volatile("s_waitcnt vmcnt(0)" ::: "memory");
      __builtin_amdgcn_s_barrier();
      if (ks + 2 < 16) {
#pragma unroll
        for (int s = 0; s < 2; s++) {
          int st = ks + 2 + s, bf = st & 3;
          gl_lds16(ga + st * 32, As + bf * 2048 + wv * 512);
#pragma unroll
          for (int rr = 0; rr < 2; rr++)
            gl_lds16(gb + st * 32 + rr * b64, Bs + bf * 4096 + rr * 2048 + wv * 512);
        }
      }
#pragma unroll
      for (int hs = 0; hs < 2; hs++) {
        int cur = (ks + hs) & 3;
        short8 av[2], bv[4];
#pragma unroll
        for (int ti = 0; ti < 2; ti++)
          av[ti] = *(const short8*)&As[cur * 2048 + (wm + ti * 16 + l15) * 32 + aswz];
#pragma unroll
        for (int tj = 0; tj < 4; tj++)
          bv[tj] = *(const short8*)&Bs[cur * 4096 + (wn + tj * 16 + l15) * 32 + aswz];
#pragma unroll
        for (int ti = 0; ti < 2; ti++)
#pragma unroll
          for (int tj = 0; tj < 4; tj++)
            acc[ti][tj] = __builtin_amdgcn_mfma_f32_16x16x32_bf16(av[ti], bv[tj], acc[ti][tj], 0, 0, 0);
      }
    }

#pragma unroll
    for (int ti = 0; ti < 2; ti++) {
#pragma unroll
      for (int tj = 0; tj < 4; tj++) {
#pragma unroll
        for (int r = 0; r < 4; r++) {
          int gm = m0 + wm + ti * 16 + quad * 4 + r;
          int n = n0 + wn + tj * 16 + l15;
          float v = acc[ti][tj][r] + in_b[n];
          int bb = gm >> 10, tt = gm & 1023;
          if (n < 512) {
            int h = n >> 6, d = n & 63;
            qp[((long)(bb * 8 + h) * 1024 + tt) * 64 + d] = f2b(v * 0.18033688011112042f);
          } else if (n < 1024) {
            int n2 = n - 512, h = n2 >> 6, d = n2 & 63;
            kp[((long)(bb * 8 + h) * 1024 + tt) * 64 + d] = f2b(v);
          } else {
            int n2 = n - 1024, h = n2 >> 6, d = n2 & 63;
            vTp[((long)(bb * 8 + h) * 64 + d) * 1024 + tt] = f2b(v);   // transposed direct
          }
        }
      }
    }
  } else {
    // ----- trXn: 64x64 tiled transpose of xn -----
    ushort_t* tile = smem;   // 8 KB
    int b2 = bid - 1536;
    int z = b2 >> 7, r0 = ((b2 >> 3) & 15) * 64, c0 = (b2 & 7) * 64;
    const ushort_t* src = xn + (long)z * 1024 * 512;
    ushort_t* dst = xnT + (long)z * 1024 * 512;
    int tr = tid >> 2;
    const ushort_t* s = src + (long)(r0 + tr) * 512 + c0;
    int g = (tr + (tr >> 4)) & 7;
#pragma unroll
    for (int u = 0; u < 2; u++) {
      int c = (tid & 3) + u * 4;
      *(uint4*)&tile[tr * 64 + (c ^ g) * 8] = *(const uint4*)(s + c * 8);
    }
    __syncthreads();
    int oc = tid >> 2, ob = (tid & 3) * 16;
    U16x8 o0, o1;
#pragma unroll
    for (int j = 0; j < 16; j++) {
      int r = ob + j;
      int gg = (r + (r >> 4)) & 7;
      ushort_t val = tile[r * 64 + (((oc >> 3) ^ gg)) * 8 + (oc & 7)];
      if (j < 8) o0.s[j] = val; else o1.s[j - 8] = val;
    }
    ushort_t* d = dst + (long)(c0 + oc) * 1024 + r0 + ob;
    *(uint4*)d = o0.v;
    *(uint4*)(d + 8) = o1.v;
  }
}

// ---- quad-buffered MFMA GEMM, single-barrier schedule (r7-verified best form) ----
struct GemmP {
  const ushort_t* A; const ushort_t* Bm;
  long sA, sB, sC;
  int lda, ldb, ldc, K;
  const float* biasf;
  const float* residf;
  const ushort_t* auxb;
  float* outf;
  ushort_t* outb;
  ushort_t* qp; ushort_t* kp; ushort_t* vp;
  const float* gate;
};

template <int BM, int BN, int EPI>
__global__ __launch_bounds__(256) void gemm_k(GemmP p) {
  constexpr int TI = BM / 32, TJ = BN / 32;
  constexpr int RA = BM / 64, RB = BN / 64;
  __shared__ ushort_t As[4][BM * 32];
  __shared__ ushort_t Bs[4][BN * 32];
  int tid = threadIdx.x, wv = tid >> 6, lane = tid & 63;
  int quad = lane >> 4, l15 = lane & 15;
  int bl = blockIdx.x + gridDim.x * blockIdx.y;
  int m0 = (bl % gridDim.y) * BM;
  int n0 = (bl / gridDim.y) * BN;
  const ushort_t* A = p.A;
  const ushort_t* Bm = p.Bm;
  int wm = (wv & 1) * (BM / 2), wn = (wv >> 1) * (BN / 2);
  f32x4 acc[TI][TJ];
#pragma unroll
  for (int i = 0; i < TI; i++)
#pragma unroll
    for (int j = 0; j < TJ; j++)
#pragma unroll
      for (int r = 0; r < 4; r++) acc[i][j][r] = 0.f;

  int srow = tid >> 2;
  int sc = ((tid & 3) ^ ((tid >> 3) & 3)) * 8;
  const ushort_t* ga = A + (long)(m0 + srow) * p.lda + sc;
  const ushort_t* gb = Bm + (long)(n0 + srow) * p.ldb + sc;
  long a64 = (long)64 * p.lda, b64 = (long)64 * p.ldb;
  int aswz = (quad ^ ((l15 >> 1) & 3)) * 8;
  int nsteps = p.K >> 5;

#pragma unroll
  for (int s = 0; s < 2; s++) {
#pragma unroll
    for (int rr = 0; rr < RA; rr++)
      gl_lds16(ga + s * 32 + rr * a64, As[s] + rr * 2048 + wv * 512);
#pragma unroll
    for (int rr = 0; rr < RB; rr++)
      gl_lds16(gb + s * 32 + rr * b64, Bs[s] + rr * 2048 + wv * 512);
  }

  for (int ks = 0; ks < nsteps; ks += 2) {
    asm volatile("s_waitcnt vmcnt(0)" ::: "memory");
    __builtin_amdgcn_s_barrier();
    if (ks + 2 < nsteps) {
#pragma unroll
      for (int s = 0; s < 2; s++) {
        int st = ks + 2 + s, bf = st & 3;
        const ushort_t* a0 = ga + st * 32;
        const ushort_t* b0 = gb + st * 32;
#pragma unroll
        for (int rr = 0; rr < RA; rr++)
          gl_lds16(a0 + rr * a64, As[bf] + rr * 2048 + wv * 512);
#pragma unroll
        for (int rr = 0; rr < RB; rr++)
          gl_lds16(b0 + rr * b64, Bs[bf] + rr * 2048 + wv * 512);
      }
    }
#pragma unroll
    for (int hs = 0; hs < 2; hs++) {
      int cur = (ks + hs) & 3;
      short8 av[TI], bv[TJ];
#pragma unroll
      for (int ti = 0; ti < TI; ti++)
        av[ti] = *(const short8*)&As[cur][(wm + ti * 16 + l15) * 32 + aswz];
#pragma unroll
      for (int tj = 0; tj < TJ; tj++)
        bv[tj] = *(const short8*)&Bs[cur][(wn + tj * 16 + l15) * 32 + aswz];
#pragma unroll
      for (int ti = 0; ti < TI; ti++)
#pragma unroll
        for (int tj = 0; tj < TJ; tj++)
          acc[ti][tj] = __builtin_amdgcn_mfma_f32_16x16x32_bf16(av[ti], bv[tj], acc[ti][tj], 0, 0, 0);
    }
  }

  float g = 0.f;
  if constexpr (EPI == 2) g = 1.f / (1.f + expf(-p.gate[0]));
#pragma unroll
  for (int ti = 0; ti < TI; ti++) {
#pragma unroll
    for (int tj = 0; tj < TJ; tj++) {
#pragma unroll
      for (int r = 0; r < 4; r++) {
        int gm = m0 + wm + ti * 16 + quad * 4 + r;
        int n = n0 + wn + tj * 16 + l15;
        float v = acc[ti][tj][r];
        if constexpr (EPI == 2) {
          v += p.biasf[n];
          long idx = (long)gm * 512 + n;
          p.outb[idx] = f2b(p.residf[idx] + g * v + (1.f - g) * b2f(p.auxb[idx]));
        } else if constexpr (EPI == 3) {
          v += p.biasf[n];
          p.outb[(long)gm * p.ldc + n] = f2b(gelu_fast(v));
        } else {  // EPI == 4
          v += p.biasf[n];
          long idx = (long)gm * 512 + n;
          p.outf[idx] = v + b2f(p.auxb[idx]);
        }
      }
    }
  }
}

// ---- merged flash (blocks 0..511) + kernel_out GEMM (blocks 512..1023) ----
__global__ __launch_bounds__(256) void fk_kernel(const ushort_t* __restrict__ q,
                                                 const ushort_t* __restrict__ k,
                                                 const ushort_t* __restrict__ vT,
                                                 ushort_t* __restrict__ ctx,
                                                 const ushort_t* __restrict__ kwp,
                                                 const ushort_t* __restrict__ xnT,
                                                 ushort_t* __restrict__ ko) {
  __shared__ __align__(16) ushort_t smem[24576];   // 48 KB
  int b = blockIdx.x;
  int tid = threadIdx.x, wv = tid >> 6, lane = tid & 63;
  int quad = lane >> 4, l15 = lane & 15;

  if (b < 512) {
    int bh = b & 63;
    int q0 = (b >> 6) * 128;
    ushort_t* Ksp = smem;
    ushort_t* Vtp = smem + 8192;
    ushort_t* Ptp = smem + 16384;
    int wm = wv * 32;

    short8 qf[2][2];
#pragma unroll
    for (int tq = 0; tq < 2; tq++)
#pragma unroll
      for (int kk2 = 0; kk2 < 2; kk2++)
        qf[tq][kk2] = *(const short8*)&q[((long)bh * 1024 + q0 + wm + tq * 16 + l15) * 64 + kk2 * 32 + quad * 8];

    int srow = tid >> 3;
    int sc = ((tid & 7) ^ ((tid >> 3) & 7)) * 8;
#pragma unroll
    for (int e = 0; e < 2; e++) {
      gl_lds16(&k[((long)bh * 1024 + e * 32 + srow) * 64 + sc], Ksp + e * 2048 + wv * 512);
      gl_lds16(&vT[((long)bh * 64 + e * 32 + srow) * 1024 + sc], Vtp + e * 2048 + wv * 512);
    }

    f32x4 O[2][4];
#pragma unroll
    for (int tq = 0; tq < 2; tq++)
#pragma unroll
      for (int td = 0; td < 4; td++)
#pragma unroll
        for (int r = 0; r < 4; r++) O[tq][td][r] = 0.f;
    float ls[2] = {0.f, 0.f};

    int pswz = (l15 & 7) << 1;
    for (int kt = 0; kt < 16; kt++) {
      int cur = kt & 1;
      asm volatile("s_waitcnt vmcnt(0)" ::: "memory");
      __builtin_amdgcn_s_barrier();
      if (kt + 1 < 16) {
#pragma unroll
        for (int e = 0; e < 2; e++) {
          gl_lds16(&k[((long)bh * 1024 + (kt + 1) * 64 + e * 32 + srow) * 64 + sc], Ksp + (cur ^ 1) * 4096 + e * 2048 + wv * 512);
          gl_lds16(&vT[((long)bh * 64 + e * 32 + srow) * 1024 + (kt + 1) * 64 + sc], Vtp + (cur ^ 1) * 4096 + e * 2048 + wv * 512);
        }
      }
#pragma unroll
      for (int tq = 0; tq < 2; tq++) {
        f32x4 S[4];
#pragma unroll
        for (int tk = 0; tk < 4; tk++) {
#pragma unroll
          for (int r = 0; r < 4; r++) S[tk][r] = 0.f;
#pragma unroll
          for (int kk2 = 0; kk2 < 2; kk2++) {
            short8 kf = *(const short8*)&Ksp[cur * 4096 + (tk * 16 + l15) * 64 + ((kk2 * 4 + quad) ^ (l15 & 7)) * 8];
            S[tk] = __builtin_amdgcn_mfma_f32_16x16x32_bf16(kf, qf[tq][kk2], S[tk], 0, 0, 0);
          }
        }
#pragma unroll
        for (int tk = 0; tk < 4; tk++) {
          float p0 = exp2f(S[tk][0]);
          float p1 = exp2f(S[tk][1]);
          float p2 = exp2f(S[tk][2]);
          float p3 = exp2f(S[tk][3]);
          ls[tq] += (p0 + p1) + (p2 + p3);
          unsigned lo = __builtin_amdgcn_perm(__float_as_uint(p1), __float_as_uint(p0), 0x07060302u);
          unsigned hi = __builtin_amdgcn_perm(__float_as_uint(p3), __float_as_uint(p2), 0x07060302u);
          int gnum = (tk * 4 + quad) ^ pswz;
          uint2 pr; pr.x = lo; pr.y = hi;
          *(uint2*)&Ptp[(wm + tq * 16 + l15) * 64 + gnum * 4] = pr;
        }
      }
#pragma unroll
      for (int tq = 0; tq < 2; tq++) {
#pragma unroll
        for (int kk2 = 0; kk2 < 2; kk2++) {
          short8 pf = *(const short8*)&Ptp[(wm + tq * 16 + l15) * 64 + (((kk2 * 8 + quad * 2) ^ pswz)) * 4];
#pragma unroll
          for (int td = 0; td < 4; td++) {
            short8 vf = *(const short8*)&Vtp[cur * 4096 + (td * 16 + l15) * 64 + ((kk2 * 4 + quad) ^ (l15 & 7)) * 8];
            O[tq][td] = __builtin_amdgcn_mfma_f32_16x16x32_bf16(pf, vf, O[tq][td], 0, 0, 0);
          }
        }
      }
    }
#pragma unroll
    for (int tq = 0; tq < 2; tq++) {
      ls[tq] += __shfl_xor(ls[tq], 16);
      ls[tq] += __shfl_xor(ls[tq], 32);
    }
    int bb = bh >> 3, h = bh & 7;
#pragma unroll
    for (int tq = 0; tq < 2; tq++) {
#pragma unroll
      for (int r = 0; r < 4; r++) {
        int qrow = quad * 4 + r;
        float inv = 1.f / __shfl(ls[tq], (lane & 48) | qrow);
        long row = (long)bb * 1024 + q0 + wm + tq * 16 + qrow;
#pragma unroll
        for (int td = 0; td < 4; td++)
          ctx[row * 512 + h * 64 + td * 16 + l15] = f2b(O[tq][td][r] * inv);
      }
    }
  } else {
    int b2 = b - 512;
    int z = b2 >> 6, bl = b2 & 63;
    int m0 = (bl & 15) * 64;
    int n0 = (bl >> 4) * 128;
    const ushort_t* A = kwp + (long)z * (1024L * 1024);
    const ushort_t* Bm = xnT + (long)z * (512L * 1024);
    ushort_t* Asp = smem;
    ushort_t* Bsp = smem + 8192;
    int wm = (wv & 1) * 32, wn = (wv >> 1) * 64;
    f32x4 acc[2][4];
#pragma unroll
    for (int i = 0; i < 2; i++)
#pragma unroll
      for (int j = 0; j < 4; j++)
#pragma unroll
        for (int r = 0; r < 4; r++) acc[i][j][r] = 0.f;

    int srow = tid >> 2;
    int sc = ((tid & 3) ^ ((tid >> 3) & 3)) * 8;
    const ushort_t* ga = A + (long)(m0 + srow) * 1024 + sc;
    const ushort_t* gb = Bm + (long)(n0 + srow) * 1024 + sc;
    const long a64 = 64L * 1024, b64 = 64L * 1024;
    int aswz = (quad ^ ((l15 >> 1) & 3)) * 8;

#pragma unroll
    for (int s = 0; s < 2; s++) {
      gl_lds16(ga + s * 32, Asp + s * 2048 + wv * 512);
#pragma unroll
      for (int rr = 0; rr < 2; rr++)
        gl_lds16(gb + s * 32 + rr * b64, Bsp + s * 4096 + rr * 2048 + wv * 512);
    }

    for (int ks = 0; ks < 32; ks += 2) {
      asm volatile("s_waitcnt vmcnt(0)" ::: "memory");
      __builtin_amdgcn_s_barrier();
      if (ks + 2 < 32) {
#pragma unroll
        for (int s = 0; s < 2; s++) {
          int st = ks + 2 + s, bf = st & 3;
          gl_lds16(ga + st * 32, Asp + bf * 2048 + wv * 512);
#pragma unroll
          for (int rr = 0; rr < 2; rr++)
            gl_lds16(gb + st * 32 + rr * b64, Bsp + bf * 4096 + rr * 2048 + wv * 512);
        }
      }
#pragma unroll
      for (int hs = 0; hs < 2; hs++) {
        int cur = (ks + hs) & 3;
        short8 av[2], bv[4];
#pragma unroll
        for (int ti = 0; ti < 2; ti++)
          av[ti] = *(const short8*)&Asp[cur * 2048 + (wm + ti * 16 + l15) * 32 + aswz];
#pragma unroll
        for (int tj = 0; tj < 4; tj++)
          bv[tj] = *(const short8*)&Bsp[cur * 4096 + (wn + tj * 16 + l15) * 32 + aswz];
#pragma unroll
        for (int ti = 0; ti < 2; ti++)
#pragma unroll
          for (int tj = 0; tj < 4; tj++)
            acc[ti][tj] = __builtin_amdgcn_mfma_f32_16x16x32_bf16(av[ti], bv[tj], acc[ti][tj], 0, 0, 0);
      }
    }

#pragma unroll
    for (int ti = 0; ti < 2; ti++) {
#pragma unroll
      for (int tj = 0; tj < 4; tj++) {
#pragma unroll
        for (int r = 0; r < 4; r++) {
          int gm = m0 + wm + ti * 16 + quad * 4 + r;
          int n = n0 + wn + tj * 16 + l15;
          ko[(long)z * (1024L * 512) + (long)gm * 512 + n] = f2b(acc[ti][tj][r]);
        }
      }
    }
  }
}

// ---------------- launch ----------------
extern "C" void kernel_launch(void* const* d_in, const int* in_sizes, int n_in,
                              void* d_out, int out_size, void* d_ws, size_t ws_size,
                              hipStream_t stream) {
  const float* x    = (const float*)d_in[0];
  const int* posv   = (const int*)d_in[1];
  const int* posh   = (const int*)d_in[2];
  const float* n1w  = (const float*)d_in[3];
  const float* n1b  = (const float*)d_in[4];
  const float* in_w = (const float*)d_in[5];
  const float* in_b = (const float*)d_in[6];
  const float* outw = (const float*)d_in[7];
  const float* outb = (const float*)d_in[8];
  const float* n2w  = (const float*)d_in[9];
  const float* n2b  = (const float*)d_in[10];
  const float* w1   = (const float*)d_in[11];
  const float* b1   = (const float*)d_in[12];
  const float* w2   = (const float*)d_in[13];
  const float* b2   = (const float*)d_in[14];
  const float* gate = (const float*)d_in[15];
  float* out = (float*)d_out;

  char* ws = (char*)d_ws;
  const size_t MB = 1024 * 1024;
  ushort_t* q    = (ushort_t*)(ws + 0 * MB);
  ushort_t* kk   = (ushort_t*)(ws + 8 * MB);
  ushort_t* vT   = (ushort_t*)(ws + 24 * MB);
  ushort_t* kw   = (ushort_t*)(ws + 32 * MB);
  ushort_t* xn   = (ushort_t*)(ws + 48 * MB);
  ushort_t* xnT  = (ushort_t*)(ws + 56 * MB);
  ushort_t* ctx  = (ushort_t*)(ws + 64 * MB);
  ushort_t* ko   = (ushort_t*)(ws + 72 * MB);
  ushort_t* x1b  = (ushort_t*)(ws + 80 * MB);
  ushort_t* xn2  = (ushort_t*)(ws + 16 * MB);
  ushort_t* inwb = (ushort_t*)(ws + 96 * MB);
  ushort_t* owb  = (ushort_t*)(ws + 98 * MB);
  ushort_t* w1b  = (ushort_t*)(ws + 99 * MB);
  ushort_t* w2b  = (ushort_t*)(ws + 101 * MB);
  ushort_t* h    = (ushort_t*)(ws + 24 * MB);   // 32 MB overlay (vT/kw/xn dead by MLP1)

  // fused: cvt4 (3072) + ln1 (2048) + kw (8192)
  prep_kernel<<<13312, 256, 0, stream>>>(in_w, outw, w1, w2, inwb, owb, w1b, w2b,
                                         x, n1w, n1b, xn, posv, posh, kw);
  // merged: qkv GEMM (v -> vT transposed direct) + trXn
  qt_kernel<<<2560, 256, 0, stream>>>(xn, inwb, in_b, q, kk, vT, xnT);
  // merged: flash attention (512 blk) + kernel_out GEMM (512 blk)
  fk_kernel<<<1024, 256, 0, stream>>>(q, kk, vT, ctx, kw, xnT, ko);
  // std_out + gate combine -> x1 bf16
  {
    GemmP p = {};
    p.A = ctx; p.Bm = owb; p.lda = 512; p.ldb = 512; p.K = 512;
    p.biasf = outb; p.residf = x; p.auxb = ko; p.outb = x1b; p.gate = gate;
    gemm_k<64, 64, 2><<<dim3(8, 128, 1), 256, 0, stream>>>(p);
  }
  ln_b_kernel<<<2048, 256, 0, stream>>>(x1b, n2w, n2b, xn2);
  // MLP1 + GELU -> h bf16
  {
    GemmP p = {};
    p.A = xn2; p.Bm = w1b; p.lda = 512; p.ldb = 512; p.ldc = 2048; p.K = 512;
    p.biasf = b1; p.outb = h;
    gemm_k<64, 128, 3><<<dim3(16, 128, 1), 256, 0, stream>>>(p);
  }
  // MLP2 + residual(x1b) -> out f32
  {
    GemmP p = {};
    p.A = h; p.Bm = w2b; p.lda = 2048; p.ldb = 2048; p.K = 2048;
    p.biasf = b2; p.auxb = x1b; p.outf = out;
    gemm_k<64, 128, 4><<<dim3(4, 128, 1), 256, 0, stream>>>(p);
  }
}

// Round 12
// 264.102 us; speedup vs baseline: 1.0119x; 1.0119x over previous
//
#include <hip/hip_runtime.h>
#include <hip/hip_bf16.h>
#include <math.h>

typedef unsigned short ushort_t;
typedef short short8 __attribute__((ext_vector_type(8)));
typedef float f32x4 __attribute__((ext_vector_type(4)));

__device__ __forceinline__ float b2f(ushort_t u) {
  union { unsigned u; float f; } v; v.u = ((unsigned)u) << 16; return v.f;
}
__device__ __forceinline__ ushort_t f2b(float f) {
  union { float f; unsigned u; } v; v.f = f;
  unsigned r = (v.u + 0x7FFFu + ((v.u >> 16) & 1u)) >> 16;
  return (ushort_t)r;
}
// fast GELU: tanh form, one exp2 — max abs err ~3e-4
__device__ __forceinline__ float gelu_fast(float v) {
  float u = 0.7978845608f * (v + 0.044715f * v * v * v);
  float a = fabsf(u);
  float t = exp2f(a * -2.8853900817779268f);
  float th = (1.f - t) / (1.f + t);
  th = copysignf(th, u);
  return 0.5f * v * (1.f + th);
}

union U16x8 { uint4 v; ushort_t s[8]; };

typedef const __attribute__((address_space(1))) unsigned int glb_u32;
typedef __attribute__((address_space(3))) unsigned int lds_u32;
__device__ __forceinline__ void gl_lds16(const ushort_t* g, ushort_t* l) {
  __builtin_amdgcn_global_load_lds((glb_u32*)g, (lds_u32*)l, 16, 0, 0);
}

// ------------- fused prep: cvt4 (3072 blk) + LayerNorm1 (2048 blk) -------------
__global__ __launch_bounds__(256) void prep_kernel(const float* __restrict__ s0,
                                                   const float* __restrict__ s1,
                                                   const float* __restrict__ s2,
                                                   const float* __restrict__ s3,
                                                   ushort_t* __restrict__ d0,
                                                   ushort_t* __restrict__ d1,
                                                   ushort_t* __restrict__ d2,
                                                   ushort_t* __restrict__ d3,
                                                   const float* __restrict__ x,
                                                   const float* __restrict__ w,
                                                   const float* __restrict__ b,
                                                   ushort_t* __restrict__ xnout) {
  int bid = blockIdx.x;
  int tid = threadIdx.x;
  if (bid < 3072) {
    long i = (long)bid * 256 + tid;
    const float* s; ushort_t* d; long off;
    if (i < 196608)       { s = s0; d = d0; off = i; }
    else if (i < 262144)  { s = s1; d = d1; off = i - 196608; }
    else if (i < 524288)  { s = s2; d = d2; off = i - 262144; }
    else                  { s = s3; d = d3; off = i - 524288; }
    float4 f = *(const float4*)(s + off * 4);
    union { uint2 v; ushort_t s[4]; } o;
    o.s[0] = f2b(f.x); o.s[1] = f2b(f.y); o.s[2] = f2b(f.z); o.s[3] = f2b(f.w);
    *(uint2*)(d + off * 4) = o.v;
  } else {
    int wave = tid >> 6, lane = tid & 63;
    long token = (long)(bid - 3072) * 4 + wave;
    const float* xr = x + token * 512 + lane * 8;
    float4 a0 = *(const float4*)xr;
    float4 a1 = *(const float4*)(xr + 4);
    float xf[8] = {a0.x, a0.y, a0.z, a0.w, a1.x, a1.y, a1.z, a1.w};
    float s = 0.f, sq = 0.f;
#pragma unroll
    for (int i = 0; i < 8; i++) { s += xf[i]; sq += xf[i] * xf[i]; }
#pragma unroll
    for (int off = 1; off < 64; off <<= 1) { s += __shfl_xor(s, off); sq += __shfl_xor(sq, off); }
    float m = s * (1.f / 512.f);
    float var = sq * (1.f / 512.f) - m * m;
    float rs = rsqrtf(var + 1e-5f);
    float4 w0 = *(const float4*)(w + lane * 8);
    float4 w1v = *(const float4*)(w + lane * 8 + 4);
    float4 b0 = *(const float4*)(b + lane * 8);
    float4 b1v = *(const float4*)(b + lane * 8 + 4);
    float wf[8] = {w0.x, w0.y, w0.z, w0.w, w1v.x, w1v.y, w1v.z, w1v.w};
    float bf[8] = {b0.x, b0.y, b0.z, b0.w, b1v.x, b1v.y, b1v.z, b1v.w};
    U16x8 o;
#pragma unroll
    for (int i = 0; i < 8; i++) o.s[i] = f2b((xf[i] - m) * rs * wf[i] + bf[i]);
    *(uint4*)(xnout + token * 512 + lane * 8) = o.v;
  }
}

// ---------------- LayerNorm (bf16 in, bf16 out) ----------------
__global__ __launch_bounds__(256) void ln_b_kernel(const ushort_t* __restrict__ x,
                                                   const float* __restrict__ w,
                                                   const float* __restrict__ b,
                                                   ushort_t* __restrict__ out) {
  int tid = threadIdx.x, wave = tid >> 6, lane = tid & 63;
  long token = (long)blockIdx.x * 4 + wave;
  U16x8 ux; ux.v = *(const uint4*)(x + token * 512 + lane * 8);
  float xf[8], s = 0.f, sq = 0.f;
#pragma unroll
  for (int i = 0; i < 8; i++) { xf[i] = b2f(ux.s[i]); s += xf[i]; sq += xf[i] * xf[i]; }
#pragma unroll
  for (int off = 1; off < 64; off <<= 1) { s += __shfl_xor(s, off); sq += __shfl_xor(sq, off); }
  float m = s * (1.f / 512.f);
  float var = sq * (1.f / 512.f) - m * m;
  float rs = rsqrtf(var + 1e-5f);
  float4 w0 = *(const float4*)(w + lane * 8);
  float4 w1v = *(const float4*)(w + lane * 8 + 4);
  float4 b0 = *(const float4*)(b + lane * 8);
  float4 b1v = *(const float4*)(b + lane * 8 + 4);
  float wf[8] = {w0.x, w0.y, w0.z, w0.w, w1v.x, w1v.y, w1v.z, w1v.w};
  float bf[8] = {b0.x, b0.y, b0.z, b0.w, b1v.x, b1v.y, b1v.z, b1v.w};
  U16x8 o;
#pragma unroll
  for (int i = 0; i < 8; i++) o.s[i] = f2b((xf[i] - m) * rs * wf[i] + bf[i]);
  *(uint4*)(out + token * 512 + lane * 8) = o.v;
}

// ---- merged qkv GEMM (0..1535, v written transposed) + trXn (1536..2559) + kw (2560..10751) ----
// qkv, trXn, kw are mutually independent given prep (cvt+ln). kw's output feeds fk (later),
// so its blocks backfill qkv's latency slack here instead of occupying a critical-path stage.
__global__ __launch_bounds__(256) void qt_kernel(const ushort_t* __restrict__ xn,
                                                 const ushort_t* __restrict__ inwb,
                                                 const float* __restrict__ in_b,
                                                 ushort_t* __restrict__ qp,
                                                 ushort_t* __restrict__ kp,
                                                 ushort_t* __restrict__ vTp,
                                                 ushort_t* __restrict__ xnT,
                                                 const int* __restrict__ posv,
                                                 const int* __restrict__ posh,
                                                 ushort_t* __restrict__ kw) {
  __shared__ __align__(16) ushort_t smem[24576];   // 48 KB union
  int bid = blockIdx.x;
  int tid = threadIdx.x, wv = tid >> 6, lane = tid & 63;
  int quad = lane >> 4, l15 = lane & 15;

  if (bid < 1536) {
    // ----- qkv GEMM -----
    ushort_t* As = smem;            // 4 bufs x 2048
    ushort_t* Bs = smem + 8192;     // 4 bufs x 4096
    int m0 = (bid & 127) * 64;
    int n0 = (bid >> 7) * 128;
    int wm = (wv & 1) * 32, wn = (wv >> 1) * 64;
    f32x4 acc[2][4];
#pragma unroll
    for (int i = 0; i < 2; i++)
#pragma unroll
      for (int j = 0; j < 4; j++)
#pragma unroll
        for (int r = 0; r < 4; r++) acc[i][j][r] = 0.f;

    int srow = tid >> 2;
    int sc = ((tid & 3) ^ ((tid >> 3) & 3)) * 8;
    const ushort_t* ga = xn + (long)(m0 + srow) * 512 + sc;
    const ushort_t* gb = inwb + (long)(n0 + srow) * 512 + sc;
    const long b64 = 64L * 512;
    int aswz = (quad ^ ((l15 >> 1) & 3)) * 8;

#pragma unroll
    for (int s = 0; s < 2; s++) {
      gl_lds16(ga + s * 32, As + s * 2048 + wv * 512);
#pragma unroll
      for (int rr = 0; rr < 2; rr++)
        gl_lds16(gb + s * 32 + rr * b64, Bs + s * 4096 + rr * 2048 + wv * 512);
    }

    for (int ks = 0; ks < 16; ks += 2) {
      asm volatile("s_waitcnt vmcnt(0)" ::: "memory");
      __builtin_amdgcn_s_barrier();
      if (ks + 2 < 16) {
#pragma unroll
        for (int s = 0; s < 2; s++) {
          int st = ks + 2 + s, bf = st & 3;
          gl_lds16(ga + st * 32, As + bf * 2048 + wv * 512);
#pragma unroll
          for (int rr = 0; rr < 2; rr++)
            gl_lds16(gb + st * 32 + rr * b64, Bs + bf * 4096 + rr * 2048 + wv * 512);
        }
      }
#pragma unroll
      for (int hs = 0; hs < 2; hs++) {
        int cur = (ks + hs) & 3;
        short8 av[2], bv[4];
#pragma unroll
        for (int ti = 0; ti < 2; ti++)
          av[ti] = *(const short8*)&As[cur * 2048 + (wm + ti * 16 + l15) * 32 + aswz];
#pragma unroll
        for (int tj = 0; tj < 4; tj++)
          bv[tj] = *(const short8*)&Bs[cur * 4096 + (wn + tj * 16 + l15) * 32 + aswz];
#pragma unroll
        for (int ti = 0; ti < 2; ti++)
#pragma unroll
          for (int tj = 0; tj < 4; tj++)
            acc[ti][tj] = __builtin_amdgcn_mfma_f32_16x16x32_bf16(av[ti], bv[tj], acc[ti][tj], 0, 0, 0);
      }
    }

#pragma unroll
    for (int ti = 0; ti < 2; ti++) {
#pragma unroll
      for (int tj = 0; tj < 4; tj++) {
#pragma unroll
        for (int r = 0; r < 4; r++) {
          int gm = m0 + wm + ti * 16 + quad * 4 + r;
          int n = n0 + wn + tj * 16 + l15;
          float v = acc[ti][tj][r] + in_b[n];
          int bb = gm >> 10, tt = gm & 1023;
          if (n < 512) {
            int h = n >> 6, d = n & 63;
            qp[((long)(bb * 8 + h) * 1024 + tt) * 64 + d] = f2b(v * 0.18033688011112042f);
          } else if (n < 1024) {
            int n2 = n - 512, h = n2 >> 6, d = n2 & 63;
            kp[((long)(bb * 8 + h) * 1024 + tt) * 64 + d] = f2b(v);
          } else {
            int n2 = n - 1024, h = n2 >> 6, d = n2 & 63;
            vTp[((long)(bb * 8 + h) * 64 + d) * 1024 + tt] = f2b(v);   // transposed direct
          }
        }
      }
    }
  } else if (bid < 2560) {
    // ----- trXn: 64x64 tiled transpose of xn -----
    ushort_t* tile = smem;   // 8 KB
    int b2 = bid - 1536;
    int z = b2 >> 7, r0 = ((b2 >> 3) & 15) * 64, c0 = (b2 & 7) * 64;
    const ushort_t* src = xn + (long)z * 1024 * 512;
    ushort_t* dst = xnT + (long)z * 1024 * 512;
    int tr = tid >> 2;
    const ushort_t* s = src + (long)(r0 + tr) * 512 + c0;
    int g = (tr + (tr >> 4)) & 7;
#pragma unroll
    for (int u = 0; u < 2; u++) {
      int c = (tid & 3) + u * 4;
      *(uint4*)&tile[tr * 64 + (c ^ g) * 8] = *(const uint4*)(s + c * 8);
    }
    __syncthreads();
    int oc = tid >> 2, ob = (tid & 3) * 16;
    U16x8 o0, o1;
#pragma unroll
    for (int j = 0; j < 16; j++) {
      int r = ob + j;
      int gg = (r + (r >> 4)) & 7;
      ushort_t val = tile[r * 64 + (((oc >> 3) ^ gg)) * 8 + (oc & 7)];
      if (j < 8) o0.s[j] = val; else o1.s[j - 8] = val;
    }
    ushort_t* d = dst + (long)(c0 + oc) * 1024 + r0 + ob;
    *(uint4*)d = o0.v;
    *(uint4*)(d + 8) = o1.v;
  } else {
    // ----- Gaussian position kernel weights -----
    float* wsum = (float*)smem;         // 4 floats
    float* totp = (float*)smem + 4;     // 1 float
    int bb = bid - 2560;
    int bz = bb >> 10, i = bb & 1023;
    const int* pv = posv + bz * 1024;
    const int* ph = posh + bz * 1024;
    int pvi = pv[i], phi = ph[i];
    int j0 = tid * 4;
    int4 vj = *(const int4*)(pv + j0);
    int4 hj = *(const int4*)(ph + j0);
    int vv[4] = {vj.x, vj.y, vj.z, vj.w};
    int hh[4] = {hj.x, hj.y, hj.z, hj.w};
    float e[4]; float loc = 0.f;
#pragma unroll
    for (int u = 0; u < 4; u++) {
      int dv = pvi - vv[u], dh = phi - hh[u];
      e[u] = expf((float)(dv * dv + dh * dh) * (-1.f / 512.f));
      loc += e[u];
    }
#pragma unroll
    for (int off = 1; off < 64; off <<= 1) loc += __shfl_xor(loc, off);
    if ((tid & 63) == 0) wsum[tid >> 6] = loc;
    __syncthreads();
    if (tid == 0) totp[0] = wsum[0] + wsum[1] + wsum[2] + wsum[3];
    __syncthreads();
    float inv = 1.f / totp[0];
    union { uint2 v; ushort_t s[4]; } o;
#pragma unroll
    for (int u = 0; u < 4; u++) o.s[u] = f2b(e[u] * inv);
    *(uint2*)&kw[((long)(bz * 1024 + i)) * 1024 + j0] = o.v;
  }
}

// ---- quad-buffered MFMA GEMM, single-barrier schedule (r7-verified best form) ----
struct GemmP {
  const ushort_t* A; const ushort_t* Bm;
  long sA, sB, sC;
  int lda, ldb, ldc, K;
  const float* biasf;
  const float* residf;
  const ushort_t* auxb;
  float* outf;
  ushort_t* outb;
  ushort_t* qp; ushort_t* kp; ushort_t* vp;
  const float* gate;
};

template <int BM, int BN, int EPI>
__global__ __launch_bounds__(256) void gemm_k(GemmP p) {
  constexpr int TI = BM / 32, TJ = BN / 32;
  constexpr int RA = BM / 64, RB = BN / 64;
  __shared__ ushort_t As[4][BM * 32];
  __shared__ ushort_t Bs[4][BN * 32];
  int tid = threadIdx.x, wv = tid >> 6, lane = tid & 63;
  int quad = lane >> 4, l15 = lane & 15;
  int bl = blockIdx.x + gridDim.x * blockIdx.y;
  int m0 = (bl % gridDim.y) * BM;
  int n0 = (bl / gridDim.y) * BN;
  const ushort_t* A = p.A;
  const ushort_t* Bm = p.Bm;
  int wm = (wv & 1) * (BM / 2), wn = (wv >> 1) * (BN / 2);
  f32x4 acc[TI][TJ];
#pragma unroll
  for (int i = 0; i < TI; i++)
#pragma unroll
    for (int j = 0; j < TJ; j++)
#pragma unroll
      for (int r = 0; r < 4; r++) acc[i][j][r] = 0.f;

  int srow = tid >> 2;
  int sc = ((tid & 3) ^ ((tid >> 3) & 3)) * 8;
  const ushort_t* ga = A + (long)(m0 + srow) * p.lda + sc;
  const ushort_t* gb = Bm + (long)(n0 + srow) * p.ldb + sc;
  long a64 = (long)64 * p.lda, b64 = (long)64 * p.ldb;
  int aswz = (quad ^ ((l15 >> 1) & 3)) * 8;
  int nsteps = p.K >> 5;

#pragma unroll
  for (int s = 0; s < 2; s++) {
#pragma unroll
    for (int rr = 0; rr < RA; rr++)
      gl_lds16(ga + s * 32 + rr * a64, As[s] + rr * 2048 + wv * 512);
#pragma unroll
    for (int rr = 0; rr < RB; rr++)
      gl_lds16(gb + s * 32 + rr * b64, Bs[s] + rr * 2048 + wv * 512);
  }

  for (int ks = 0; ks < nsteps; ks += 2) {
    asm volatile("s_waitcnt vmcnt(0)" ::: "memory");
    __builtin_amdgcn_s_barrier();
    if (ks + 2 < nsteps) {
#pragma unroll
      for (int s = 0; s < 2; s++) {
        int st = ks + 2 + s, bf = st & 3;
        const ushort_t* a0 = ga + st * 32;
        const ushort_t* b0 = gb + st * 32;
#pragma unroll
        for (int rr = 0; rr < RA; rr++)
          gl_lds16(a0 + rr * a64, As[bf] + rr * 2048 + wv * 512);
#pragma unroll
        for (int rr = 0; rr < RB; rr++)
          gl_lds16(b0 + rr * b64, Bs[bf] + rr * 2048 + wv * 512);
      }
    }
#pragma unroll
    for (int hs = 0; hs < 2; hs++) {
      int cur = (ks + hs) & 3;
      short8 av[TI], bv[TJ];
#pragma unroll
      for (int ti = 0; ti < TI; ti++)
        av[ti] = *(const short8*)&As[cur][(wm + ti * 16 + l15) * 32 + aswz];
#pragma unroll
      for (int tj = 0; tj < TJ; tj++)
        bv[tj] = *(const short8*)&Bs[cur][(wn + tj * 16 + l15) * 32 + aswz];
#pragma unroll
      for (int ti = 0; ti < TI; ti++)
#pragma unroll
        for (int tj = 0; tj < TJ; tj++)
          acc[ti][tj] = __builtin_amdgcn_mfma_f32_16x16x32_bf16(av[ti], bv[tj], acc[ti][tj], 0, 0, 0);
    }
  }

  float g = 0.f;
  if constexpr (EPI == 2) g = 1.f / (1.f + expf(-p.gate[0]));
#pragma unroll
  for (int ti = 0; ti < TI; ti++) {
#pragma unroll
    for (int tj = 0; tj < TJ; tj++) {
#pragma unroll
      for (int r = 0; r < 4; r++) {
        int gm = m0 + wm + ti * 16 + quad * 4 + r;
        int n = n0 + wn + tj * 16 + l15;
        float v = acc[ti][tj][r];
        if constexpr (EPI == 2) {
          v += p.biasf[n];
          long idx = (long)gm * 512 + n;
          p.outb[idx] = f2b(p.residf[idx] + g * v + (1.f - g) * b2f(p.auxb[idx]));
        } else if constexpr (EPI == 3) {
          v += p.biasf[n];
          p.outb[(long)gm * p.ldc + n] = f2b(gelu_fast(v));
        } else {  // EPI == 4
          v += p.biasf[n];
          long idx = (long)gm * 512 + n;
          p.outf[idx] = v + b2f(p.auxb[idx]);
        }
      }
    }
  }
}

// ---- merged flash (blocks 0..511) + kernel_out GEMM (blocks 512..1023) ----
__global__ __launch_bounds__(256) void fk_kernel(const ushort_t* __restrict__ q,
                                                 const ushort_t* __restrict__ k,
                                                 const ushort_t* __restrict__ vT,
                                                 ushort_t* __restrict__ ctx,
                                                 const ushort_t* __restrict__ kwp,
                                                 const ushort_t* __restrict__ xnT,
                                                 ushort_t* __restrict__ ko) {
  __shared__ __align__(16) ushort_t smem[24576];   // 48 KB
  int b = blockIdx.x;
  int tid = threadIdx.x, wv = tid >> 6, lane = tid & 63;
  int quad = lane >> 4, l15 = lane & 15;

  if (b < 512) {
    int bh = b & 63;
    int q0 = (b >> 6) * 128;
    ushort_t* Ksp = smem;
    ushort_t* Vtp = smem + 8192;
    ushort_t* Ptp = smem + 16384;
    int wm = wv * 32;

    short8 qf[2][2];
#pragma unroll
    for (int tq = 0; tq < 2; tq++)
#pragma unroll
      for (int kk2 = 0; kk2 < 2; kk2++)
        qf[tq][kk2] = *(const short8*)&q[((long)bh * 1024 + q0 + wm + tq * 16 + l15) * 64 + kk2 * 32 + quad * 8];

    int srow = tid >> 3;
    int sc = ((tid & 7) ^ ((tid >> 3) & 7)) * 8;
#pragma unroll
    for (int e = 0; e < 2; e++) {
      gl_lds16(&k[((long)bh * 1024 + e * 32 + srow) * 64 + sc], Ksp + e * 2048 + wv * 512);
      gl_lds16(&vT[((long)bh * 64 + e * 32 + srow) * 1024 + sc], Vtp + e * 2048 + wv * 512);
    }

    f32x4 O[2][4];
#pragma unroll
    for (int tq = 0; tq < 2; tq++)
#pragma unroll
      for (int td = 0; td < 4; td++)
#pragma unroll
        for (int r = 0; r < 4; r++) O[tq][td][r] = 0.f;
    float ls[2] = {0.f, 0.f};

    int pswz = (l15 & 7) << 1;
    for (int kt = 0; kt < 16; kt++) {
      int cur = kt & 1;
      asm volatile("s_waitcnt vmcnt(0)" ::: "memory");
      __builtin_amdgcn_s_barrier();
      if (kt + 1 < 16) {
#pragma unroll
        for (int e = 0; e < 2; e++) {
          gl_lds16(&k[((long)bh * 1024 + (kt + 1) * 64 + e * 32 + srow) * 64 + sc], Ksp + (cur ^ 1) * 4096 + e * 2048 + wv * 512);
          gl_lds16(&vT[((long)bh * 64 + e * 32 + srow) * 1024 + (kt + 1) * 64 + sc], Vtp + (cur ^ 1) * 4096 + e * 2048 + wv * 512);
        }
      }
#pragma unroll
      for (int tq = 0; tq < 2; tq++) {
        f32x4 S[4];
#pragma unroll
        for (int tk = 0; tk < 4; tk++) {
#pragma unroll
          for (int r = 0; r < 4; r++) S[tk][r] = 0.f;
#pragma unroll
          for (int kk2 = 0; kk2 < 2; kk2++) {
            short8 kf = *(const short8*)&Ksp[cur * 4096 + (tk * 16 + l15) * 64 + ((kk2 * 4 + quad) ^ (l15 & 7)) * 8];
            S[tk] = __builtin_amdgcn_mfma_f32_16x16x32_bf16(kf, qf[tq][kk2], S[tk], 0, 0, 0);
          }
        }
#pragma unroll
        for (int tk = 0; tk < 4; tk++) {
          float p0 = exp2f(S[tk][0]);
          float p1 = exp2f(S[tk][1]);
          float p2 = exp2f(S[tk][2]);
          float p3 = exp2f(S[tk][3]);
          ls[tq] += (p0 + p1) + (p2 + p3);
          unsigned lo = __builtin_amdgcn_perm(__float_as_uint(p1), __float_as_uint(p0), 0x07060302u);
          unsigned hi = __builtin_amdgcn_perm(__float_as_uint(p3), __float_as_uint(p2), 0x07060302u);
          int gnum = (tk * 4 + quad) ^ pswz;
          uint2 pr; pr.x = lo; pr.y = hi;
          *(uint2*)&Ptp[(wm + tq * 16 + l15) * 64 + gnum * 4] = pr;
        }
      }
#pragma unroll
      for (int tq = 0; tq < 2; tq++) {
#pragma unroll
        for (int kk2 = 0; kk2 < 2; kk2++) {
          short8 pf = *(const short8*)&Ptp[(wm + tq * 16 + l15) * 64 + (((kk2 * 8 + quad * 2) ^ pswz)) * 4];
#pragma unroll
          for (int td = 0; td < 4; td++) {
            short8 vf = *(const short8*)&Vtp[cur * 4096 + (td * 16 + l15) * 64 + ((kk2 * 4 + quad) ^ (l15 & 7)) * 8];
            O[tq][td] = __builtin_amdgcn_mfma_f32_16x16x32_bf16(pf, vf, O[tq][td], 0, 0, 0);
          }
        }
      }
    }
#pragma unroll
    for (int tq = 0; tq < 2; tq++) {
      ls[tq] += __shfl_xor(ls[tq], 16);
      ls[tq] += __shfl_xor(ls[tq], 32);
    }
    int bb = bh >> 3, h = bh & 7;
#pragma unroll
    for (int tq = 0; tq < 2; tq++) {
#pragma unroll
      for (int r = 0; r < 4; r++) {
        int qrow = quad * 4 + r;
        float inv = 1.f / __shfl(ls[tq], (lane & 48) | qrow);
        long row = (long)bb * 1024 + q0 + wm + tq * 16 + qrow;
#pragma unroll
        for (int td = 0; td < 4; td++)
          ctx[row * 512 + h * 64 + td * 16 + l15] = f2b(O[tq][td][r] * inv);
      }
    }
  } else {
    int b2 = b - 512;
    int z = b2 >> 6, bl = b2 & 63;
    int m0 = (bl & 15) * 64;
    int n0 = (bl >> 4) * 128;
    const ushort_t* A = kwp + (long)z * (1024L * 1024);
    const ushort_t* Bm = xnT + (long)z * (512L * 1024);
    ushort_t* Asp = smem;
    ushort_t* Bsp = smem + 8192;
    int wm = (wv & 1) * 32, wn = (wv >> 1) * 64;
    f32x4 acc[2][4];
#pragma unroll
    for (int i = 0; i < 2; i++)
#pragma unroll
      for (int j = 0; j < 4; j++)
#pragma unroll
        for (int r = 0; r < 4; r++) acc[i][j][r] = 0.f;

    int srow = tid >> 2;
    int sc = ((tid & 3) ^ ((tid >> 3) & 3)) * 8;
    const ushort_t* ga = A + (long)(m0 + srow) * 1024 + sc;
    const ushort_t* gb = Bm + (long)(n0 + srow) * 1024 + sc;
    const long a64 = 64L * 1024, b64 = 64L * 1024;
    int aswz = (quad ^ ((l15 >> 1) & 3)) * 8;

#pragma unroll
    for (int s = 0; s < 2; s++) {
      gl_lds16(ga + s * 32, Asp + s * 2048 + wv * 512);
#pragma unroll
      for (int rr = 0; rr < 2; rr++)
        gl_lds16(gb + s * 32 + rr * b64, Bsp + s * 4096 + rr * 2048 + wv * 512);
    }

    for (int ks = 0; ks < 32; ks += 2) {
      asm volatile("s_waitcnt vmcnt(0)" ::: "memory");
      __builtin_amdgcn_s_barrier();
      if (ks + 2 < 32) {
#pragma unroll
        for (int s = 0; s < 2; s++) {
          int st = ks + 2 + s, bf = st & 3;
          gl_lds16(ga + st * 32, Asp + bf * 2048 + wv * 512);
#pragma unroll
          for (int rr = 0; rr < 2; rr++)
            gl_lds16(gb + st * 32 + rr * b64, Bsp + bf * 4096 + rr * 2048 + wv * 512);
        }
      }
#pragma unroll
      for (int hs = 0; hs < 2; hs++) {
        int cur = (ks + hs) & 3;
        short8 av[2], bv[4];
#pragma unroll
        for (int ti = 0; ti < 2; ti++)
          av[ti] = *(const short8*)&Asp[cur * 2048 + (wm + ti * 16 + l15) * 32 + aswz];
#pragma unroll
        for (int tj = 0; tj < 4; tj++)
          bv[tj] = *(const short8*)&Bsp[cur * 4096 + (wn + tj * 16 + l15) * 32 + aswz];
#pragma unroll
        for (int ti = 0; ti < 2; ti++)
#pragma unroll
          for (int tj = 0; tj < 4; tj++)
            acc[ti][tj] = __builtin_amdgcn_mfma_f32_16x16x32_bf16(av[ti], bv[tj], acc[ti][tj], 0, 0, 0);
      }
    }

#pragma unroll
    for (int ti = 0; ti < 2; ti++) {
#pragma unroll
      for (int tj = 0; tj < 4; tj++) {
#pragma unroll
        for (int r = 0; r < 4; r++) {
          int gm = m0 + wm + ti * 16 + quad * 4 + r;
          int n = n0 + wn + tj * 16 + l15;
          ko[(long)z * (1024L * 512) + (long)gm * 512 + n] = f2b(acc[ti][tj][r]);
        }
      }
    }
  }
}

// ---------------- launch ----------------
extern "C" void kernel_launch(void* const* d_in, const int* in_sizes, int n_in,
                              void* d_out, int out_size, void* d_ws, size_t ws_size,
                              hipStream_t stream) {
  const float* x    = (const float*)d_in[0];
  const int* posv   = (const int*)d_in[1];
  const int* posh   = (const int*)d_in[2];
  const float* n1w  = (const float*)d_in[3];
  const float* n1b  = (const float*)d_in[4];
  const float* in_w = (const float*)d_in[5];
  const float* in_b = (const float*)d_in[6];
  const float* outw = (const float*)d_in[7];
  const float* outb = (const float*)d_in[8];
  const float* n2w  = (const float*)d_in[9];
  const float* n2b  = (const float*)d_in[10];
  const float* w1   = (const float*)d_in[11];
  const float* b1   = (const float*)d_in[12];
  const float* w2   = (const float*)d_in[13];
  const float* b2   = (const float*)d_in[14];
  const float* gate = (const float*)d_in[15];
  float* out = (float*)d_out;

  char* ws = (char*)d_ws;
  const size_t MB = 1024 * 1024;
  ushort_t* q    = (ushort_t*)(ws + 0 * MB);
  ushort_t* kk   = (ushort_t*)(ws + 8 * MB);
  ushort_t* vT   = (ushort_t*)(ws + 24 * MB);
  ushort_t* kw   = (ushort_t*)(ws + 32 * MB);
  ushort_t* xn   = (ushort_t*)(ws + 48 * MB);
  ushort_t* xnT  = (ushort_t*)(ws + 56 * MB);
  ushort_t* ctx  = (ushort_t*)(ws + 64 * MB);
  ushort_t* ko   = (ushort_t*)(ws + 72 * MB);
  ushort_t* x1b  = (ushort_t*)(ws + 80 * MB);
  ushort_t* xn2  = (ushort_t*)(ws + 16 * MB);
  ushort_t* inwb = (ushort_t*)(ws + 96 * MB);
  ushort_t* owb  = (ushort_t*)(ws + 98 * MB);
  ushort_t* w1b  = (ushort_t*)(ws + 99 * MB);
  ushort_t* w2b  = (ushort_t*)(ws + 101 * MB);
  ushort_t* h    = (ushort_t*)(ws + 24 * MB);   // 32 MB overlay (vT/kw/xn dead by MLP1)

  // fused: cvt4 (3072) + ln1 (2048)
  prep_kernel<<<5120, 256, 0, stream>>>(in_w, outw, w1, w2, inwb, owb, w1b, w2b,
                                        x, n1w, n1b, xn);
  // merged: qkv GEMM (v -> vT transposed direct) + trXn + kw
  qt_kernel<<<10752, 256, 0, stream>>>(xn, inwb, in_b, q, kk, vT, xnT, posv, posh, kw);
  // merged: flash attention (512 blk) + kernel_out GEMM (512 blk)
  fk_kernel<<<1024, 256, 0, stream>>>(q, kk, vT, ctx, kw, xnT, ko);
  // std_out + gate combine -> x1 bf16
  {
    GemmP p = {};
    p.A = ctx; p.Bm = owb; p.lda = 512; p.ldb = 512; p.K = 512;
    p.biasf = outb; p.residf = x; p.auxb = ko; p.outb = x1b; p.gate = gate;
    gemm_k<64, 64, 2><<<dim3(8, 128, 1), 256, 0, stream>>>(p);
  }
  ln_b_kernel<<<2048, 256, 0, stream>>>(x1b, n2w, n2b, xn2);
  // MLP1 + GELU -> h bf16
  {
    GemmP p = {};
    p.A = xn2; p.Bm = w1b; p.lda = 512; p.ldb = 512; p.ldc = 2048; p.K = 512;
    p.biasf = b1; p.outb = h;
    gemm_k<64, 128, 3><<<dim3(16, 128, 1), 256, 0, stream>>>(p);
  }
  // MLP2 + residual(x1b) -> out f32
  {
    GemmP p = {};
    p.A = h; p.Bm = w2b; p.lda = 2048; p.ldb = 2048; p.K = 2048;
    p.biasf = b2; p.auxb = x1b; p.outf = out;
    gemm_k<64, 128, 4><<<dim3(4, 128, 1), 256, 0, stream>>>(p);
  }
}